// Round 4
// baseline (171.719 us; speedup 1.0000x reference)
//
#include <hip/hip_runtime.h>
#include <hip/hip_bf16.h>

#define N_NODES 50000
#define K_EIG   512
#define F_DIM   128
#define NPAD    51200     // 200 splits * 256
#define NSPLITS 200
#define CHUNK   256

typedef __attribute__((ext_vector_type(8))) short bf16x8;
typedef __attribute__((ext_vector_type(4))) short s16x4;
typedef __attribute__((ext_vector_type(4))) float f32x4;

static __device__ __forceinline__ unsigned pk2(float lo, float hi) {
    unsigned short a = __builtin_bit_cast(unsigned short, __float2bfloat16(lo));
    unsigned short b = __builtin_bit_cast(unsigned short, __float2bfloat16(hi));
    return ((unsigned)b << 16) | (unsigned)a;
}

static __device__ __forceinline__ short f2bf(float f) {
    union { float f; unsigned u; } v; v.f = f;
    unsigned r = v.u + 0x7fffu + ((v.u >> 16) & 1u);   // RNE
    return (short)(r >> 16);
}

static __device__ __forceinline__ float bf2f(unsigned short u) {
    union { unsigned u; float f; } v; v.u = ((unsigned)u) << 16;
    return v.f;
}

// ---------------- prep: U -> UT[k][n(pad)] bf16 ------------------------------
__global__ __launch_bounds__(256) void prep_u(const float* __restrict__ U,
                                              unsigned* __restrict__ UT)
{
    const int n0 = blockIdx.x * 64;
    const int k0 = blockIdx.y * 64;
    const int a  = threadIdx.x & 15;
    const int b  = threadIdx.x >> 4;
    const int n  = n0 + 4 * a;
    const int k  = k0 + 4 * b;

    float r[4][4];
    #pragma unroll
    for (int j = 0; j < 4; ++j) {
        int nr = n + j;
        if (nr < N_NODES) {
            f32x4 v = *reinterpret_cast<const f32x4*>(U + (long)nr * K_EIG + k);
            r[j][0] = v[0]; r[j][1] = v[1]; r[j][2] = v[2]; r[j][3] = v[3];
        } else {
            r[j][0] = r[j][1] = r[j][2] = r[j][3] = 0.f;
        }
    }
    #pragma unroll
    for (int i = 0; i < 4; ++i) {
        unsigned* p = UT + ((long)(k + i) * NPAD + n) / 2;
        p[0] = pk2(r[0][i], r[1][i]);
        p[1] = pk2(r[2][i], r[3][i]);
    }
}

// ---------------- prep: x -> xT[f][n(pad)] bf16 ------------------------------
__global__ __launch_bounds__(256) void prep_x(const float* __restrict__ x,
                                              unsigned* __restrict__ xT)
{
    const int n0 = blockIdx.x * 64;
    const int f0 = blockIdx.y * 64;
    const int a  = threadIdx.x & 15;
    const int b  = threadIdx.x >> 4;
    const int n  = n0 + 4 * a;
    const int f  = f0 + 4 * b;

    float r[4][4];
    #pragma unroll
    for (int j = 0; j < 4; ++j) {
        int nr = n + j;
        if (nr < N_NODES) {
            f32x4 v = *reinterpret_cast<const f32x4*>(x + (long)nr * F_DIM + f);
            r[j][0] = v[0]; r[j][1] = v[1]; r[j][2] = v[2]; r[j][3] = v[3];
        } else {
            r[j][0] = r[j][1] = r[j][2] = r[j][3] = 0.f;
        }
    }
    #pragma unroll
    for (int i = 0; i < 4; ++i) {
        unsigned* p = xT + ((long)(f + i) * NPAD + n) / 2;
        p[0] = pk2(r[0][i], r[1][i]);
        p[1] = pk2(r[2][i], r[3][i]);
    }
}

// ---------------- GEMM1: partial[split][f][k] = sum_n UT[k][n]*xT[f][n] ------
__global__ __launch_bounds__(256) void k_spec(
    const unsigned short* __restrict__ UT, const unsigned short* __restrict__ xT,
    unsigned short* __restrict__ partial)
{
    const int kt    = blockIdx.x;
    const int split = blockIdx.y;
    const int tid   = threadIdx.x;
    const int wid   = tid >> 6;
    const int lane  = tid & 63;
    const int h     = lane >> 4;
    const int m     = lane & 15;
    const int k0    = kt * 64;
    const int f0    = wid * 32;
    const int nbeg  = split * CHUNK;

    f32x4 acc[4][2];
    #pragma unroll
    for (int s = 0; s < 4; ++s)
        #pragma unroll
        for (int t = 0; t < 2; ++t)
            #pragma unroll
            for (int e = 0; e < 4; ++e) acc[s][t][e] = 0.f;

    const unsigned short* Abase = UT + (long)(k0 + m) * NPAD + 8 * h;
    const unsigned short* Bbase = xT + (long)(f0 + m) * NPAD + 8 * h;

    for (int nb = nbeg; nb < nbeg + CHUNK; nb += 32) {
        bf16x8 a[4], b[2];
        #pragma unroll
        for (int s = 0; s < 4; ++s)
            a[s] = *reinterpret_cast<const bf16x8*>(Abase + (long)16 * s * NPAD + nb);
        #pragma unroll
        for (int t = 0; t < 2; ++t)
            b[t] = *reinterpret_cast<const bf16x8*>(Bbase + (long)16 * t * NPAD + nb);
        #pragma unroll
        for (int s = 0; s < 4; ++s)
            #pragma unroll
            for (int t = 0; t < 2; ++t)
                acc[s][t] = __builtin_amdgcn_mfma_f32_16x16x32_bf16(
                    a[s], b[t], acc[s][t], 0, 0, 0);
    }

    unsigned short* pbase = partial + (long)split * (F_DIM * K_EIG);
    #pragma unroll
    for (int s = 0; s < 4; ++s)
        #pragma unroll
        for (int t = 0; t < 2; ++t) {
            int k = k0 + 16 * s + 4 * h;
            int f = f0 + 16 * t + m;
            s16x4 v;
            #pragma unroll
            for (int r = 0; r < 4; ++r) v[r] = f2bf(acc[s][t][r]);
            *reinterpret_cast<s16x4*>(pbase + (long)f * K_EIG + k) = v;
        }
}

// ---------------- reduce partials, fold g, emit bf16 spec --------------------
__global__ __launch_bounds__(256) void k_reduce(
    const unsigned short* __restrict__ partial, const float* __restrict__ g,
    unsigned short* __restrict__ specbf)
{
    int idx = blockIdx.x * 256 + threadIdx.x;   // 0..65535
    float s = 0.f;
    #pragma unroll 8
    for (int p = 0; p < NSPLITS; ++p)
        s += bf2f(partial[(long)p * (F_DIM * K_EIG) + idx]);
    int k = idx & (K_EIG - 1);
    specbf[idx] = (unsigned short)f2bf(s * g[k]);
}

// ---------------- GEMM2: out[n][f] = relu(sum_k U[n][k]*specbf[f][k]) --------
// 32n x 128f per block, 1563 blocks (~6 blocks/CU, ~24 waves/CU).
// Wave tile = 16n x 64f: acc[4], 6 loads + 4 MFMAs per K-iter.
__global__ __launch_bounds__(256, 6) void k_out(
    const float* __restrict__ U, const unsigned short* __restrict__ specbf,
    float* __restrict__ out)
{
    const int tid  = threadIdx.x;
    const int wid  = tid >> 6;
    const int lane = tid & 63;
    const int h = lane >> 4, m = lane & 15;
    const int wr = wid >> 1, wc = wid & 1;
    const int nbase = blockIdx.x * 32 + wr * 16;
    const int fbase = wc * 64;

    const int n  = nbase + m;
    const int nc = (n < N_NODES) ? n : (N_NODES - 1);
    const float* Abase = U + (long)nc * K_EIG + 8 * h;
    const unsigned short* Bbase = specbf + (long)(fbase + m) * K_EIG + 8 * h;

    f32x4 acc[4];
    #pragma unroll
    for (int t = 0; t < 4; ++t)
        #pragma unroll
        for (int e = 0; e < 4; ++e) acc[t][e] = 0.f;

    #pragma unroll 4
    for (int kb = 0; kb < K_EIG; kb += 32) {
        bf16x8 a, b[4];
        f32x4 lo = *reinterpret_cast<const f32x4*>(Abase + kb);
        f32x4 hi = *reinterpret_cast<const f32x4*>(Abase + kb + 4);
        #pragma unroll
        for (int j = 0; j < 4; ++j) {
            a[j]     = f2bf(lo[j]);
            a[j + 4] = f2bf(hi[j]);
        }
        #pragma unroll
        for (int t = 0; t < 4; ++t)
            b[t] = *reinterpret_cast<const bf16x8*>(Bbase + (long)16 * t * K_EIG + kb);
        #pragma unroll
        for (int t = 0; t < 4; ++t)
            acc[t] = __builtin_amdgcn_mfma_f32_16x16x32_bf16(a, b[t], acc[t], 0, 0, 0);
    }

    #pragma unroll
    for (int r = 0; r < 4; ++r) {
        int nn = nbase + 4 * h + r;
        if (nn < N_NODES) {
            float* orow = out + (long)nn * F_DIM + fbase + m;
            #pragma unroll
            for (int t = 0; t < 4; ++t)
                orow[16 * t] = fmaxf(acc[t][r], 0.f);
        }
    }
}

// =================== fallback (round-1) path if ws too small =================
__global__ __launch_bounds__(256) void k_spec_v1(
    const float* __restrict__ U, const float* __restrict__ g,
    const float* __restrict__ x, float* __restrict__ specT)
{
    const int kt    = blockIdx.x;
    const int split = blockIdx.y;
    const int tid   = threadIdx.x;
    const int wid   = tid >> 6;
    const int lane  = tid & 63;
    const int h     = lane >> 4;
    const int m     = lane & 15;
    const int k0 = kt * 64;
    const int f0 = wid * 32;
    const int chunk1 = 782;
    const int n_start = split * chunk1;
    int n_end = n_start + chunk1;
    if (n_end > N_NODES) n_end = N_NODES;

    f32x4 acc[4][2];
    #pragma unroll
    for (int s = 0; s < 4; ++s)
        #pragma unroll
        for (int t = 0; t < 2; ++t)
            #pragma unroll
            for (int e = 0; e < 4; ++e) acc[s][t][e] = 0.f;

    for (int nb = n_start; nb < n_end; nb += 32) {
        bf16x8 a[4]; bf16x8 b[2];
        const int nrow = nb + 8 * h;
        #pragma unroll
        for (int j = 0; j < 8; ++j) {
            int nn = nrow + j;
            bool valid = (nn < n_end);
            int nc = valid ? nn : (n_end - 1);
            const float* Urow = U + (long)nc * K_EIG + k0 + m;
            const float* Xrow = x + (long)nc * F_DIM + f0 + m;
            #pragma unroll
            for (int s = 0; s < 4; ++s) {
                short bv = f2bf(Urow[16 * s]);
                a[s][j] = valid ? bv : (short)0;
            }
            #pragma unroll
            for (int t = 0; t < 2; ++t) {
                short bv = f2bf(Xrow[16 * t]);
                b[t][j] = valid ? bv : (short)0;
            }
        }
        #pragma unroll
        for (int s = 0; s < 4; ++s)
            #pragma unroll
            for (int t = 0; t < 2; ++t)
                acc[s][t] = __builtin_amdgcn_mfma_f32_16x16x32_bf16(
                    a[s], b[t], acc[s][t], 0, 0, 0);
    }
    #pragma unroll
    for (int s = 0; s < 4; ++s)
        #pragma unroll
        for (int t = 0; t < 2; ++t)
            #pragma unroll
            for (int r = 0; r < 4; ++r) {
                int k = k0 + 16 * s + 4 * h + r;
                int f = f0 + 16 * t + m;
                atomicAdd(&specT[(long)f * K_EIG + k], acc[s][t][r] * g[k]);
            }
}

__global__ __launch_bounds__(256) void k_out_v1(
    const float* __restrict__ U, const float* __restrict__ specT,
    float* __restrict__ out)
{
    const int tid  = threadIdx.x;
    const int wid  = tid >> 6;
    const int lane = tid & 63;
    const int h = lane >> 4, m = lane & 15;
    const int wr = wid >> 1, wc = wid & 1;
    const int nbase = blockIdx.x * 128 + wr * 64;
    const int fbase = wc * 64;

    f32x4 acc[4][4];
    #pragma unroll
    for (int i = 0; i < 4; ++i)
        #pragma unroll
        for (int t = 0; t < 4; ++t)
            #pragma unroll
            for (int e = 0; e < 4; ++e) acc[i][t][e] = 0.f;

    for (int kb = 0; kb < K_EIG; kb += 32) {
        bf16x8 a[4], b[4];
        #pragma unroll
        for (int i = 0; i < 4; ++i) {
            int nn = nbase + 16 * i + m;
            bool valid = (nn < N_NODES);
            int nc = valid ? nn : (N_NODES - 1);
            const f32x4* p = reinterpret_cast<const f32x4*>(
                U + (long)nc * K_EIG + kb + 8 * h);
            f32x4 lo = p[0], hi = p[1];
            #pragma unroll
            for (int j = 0; j < 4; ++j) {
                short b0 = f2bf(lo[j]), b1 = f2bf(hi[j]);
                a[i][j]     = valid ? b0 : (short)0;
                a[i][j + 4] = valid ? b1 : (short)0;
            }
        }
        #pragma unroll
        for (int t = 0; t < 4; ++t) {
            const f32x4* p = reinterpret_cast<const f32x4*>(
                specT + (long)(fbase + 16 * t + m) * K_EIG + kb + 8 * h);
            f32x4 lo = p[0], hi = p[1];
            #pragma unroll
            for (int j = 0; j < 4; ++j) {
                b[t][j]     = f2bf(lo[j]);
                b[t][j + 4] = f2bf(hi[j]);
            }
        }
        #pragma unroll
        for (int i = 0; i < 4; ++i)
            #pragma unroll
            for (int t = 0; t < 4; ++t)
                acc[i][t] = __builtin_amdgcn_mfma_f32_16x16x32_bf16(
                    a[i], b[t], acc[i][t], 0, 0, 0);
    }
    #pragma unroll
    for (int i = 0; i < 4; ++i)
        #pragma unroll
        for (int r = 0; r < 4; ++r) {
            int nn = nbase + 16 * i + 4 * h + r;
            if (nn < N_NODES) {
                float* orow = out + (long)nn * F_DIM + fbase + m;
                #pragma unroll
                for (int t = 0; t < 4; ++t)
                    orow[16 * t] = fmaxf(acc[i][t][r], 0.f);
            }
        }
}

// ============================================================================
extern "C" void kernel_launch(void* const* d_in, const int* in_sizes, int n_in,
                              void* d_out, int out_size, void* d_ws, size_t ws_size,
                              hipStream_t stream) {
    const float* U = (const float*)d_in[0];
    const float* g = (const float*)d_in[1];
    const float* x = (const float*)d_in[2];
    float* out = (float*)d_out;

    // ws layout (bytes)
    const size_t OFF_UT    = 0;                 // 512*51200*2       = 52,428,800
    const size_t OFF_XT    = 52428800;          // 128*51200*2       = 13,107,200
    const size_t OFF_PART  = 65536000;          // 200*128*512*2     = 26,214,400
    const size_t OFF_SPECB = 91750400;          // 128*512*2         =    131,072
    const size_t WS_NEEDED = 91881472;

    if (ws_size >= WS_NEEDED) {
        unsigned*       UT     = (unsigned*)((char*)d_ws + OFF_UT);
        unsigned*       xT     = (unsigned*)((char*)d_ws + OFF_XT);
        unsigned short* part   = (unsigned short*)((char*)d_ws + OFF_PART);
        unsigned short* specbf = (unsigned short*)((char*)d_ws + OFF_SPECB);

        dim3 gu(NPAD / 64, K_EIG / 64);   // 800 x 8
        prep_u<<<gu, 256, 0, stream>>>(U, UT);

        dim3 gx(NPAD / 64, F_DIM / 64);   // 800 x 2
        prep_x<<<gx, 256, 0, stream>>>(x, xT);

        dim3 g1(K_EIG / 64, NSPLITS);     // 8 x 200 = 1600 blocks
        k_spec<<<g1, 256, 0, stream>>>((const unsigned short*)UT,
                                       (const unsigned short*)xT, part);

        k_reduce<<<(K_EIG * F_DIM) / 256, 256, 0, stream>>>(part, g, specbf);

        int nb2 = (N_NODES + 31) / 32;    // 1563
        k_out<<<nb2, 256, 0, stream>>>(U, specbf, out);
    } else {
        float* specT = (float*)d_ws;      // 256 KB
        hipMemsetAsync(specT, 0, (size_t)K_EIG * F_DIM * sizeof(float), stream);
        dim3 g1(K_EIG / 64, 64);
        k_spec_v1<<<g1, 256, 0, stream>>>(U, g, x, specT);
        int nb2 = (N_NODES + 127) / 128;
        k_out_v1<<<nb2, 256, 0, stream>>>(U, specT, out);
    }
}

// Round 5
// 163.295 us; speedup vs baseline: 1.0516x; 1.0516x over previous
//
#include <hip/hip_runtime.h>
#include <hip/hip_bf16.h>

#define N_NODES 50000
#define K_EIG   512
#define F_DIM   128
#define NPAD    51200     // 200 splits * 256
#define NSPLITS 200
#define CHUNK   256

typedef __attribute__((ext_vector_type(8))) short bf16x8;
typedef __attribute__((ext_vector_type(4))) short s16x4;
typedef __attribute__((ext_vector_type(4))) float f32x4;

static __device__ __forceinline__ unsigned pk2(float lo, float hi) {
    unsigned short a = __builtin_bit_cast(unsigned short, __float2bfloat16(lo));
    unsigned short b = __builtin_bit_cast(unsigned short, __float2bfloat16(hi));
    return ((unsigned)b << 16) | (unsigned)a;
}

static __device__ __forceinline__ short f2bf(float f) {
    union { float f; unsigned u; } v; v.f = f;
    unsigned r = v.u + 0x7fffu + ((v.u >> 16) & 1u);   // RNE
    return (short)(r >> 16);
}

static __device__ __forceinline__ float bf2f(unsigned short u) {
    union { unsigned u; float f; } v; v.u = ((unsigned)u) << 16;
    return v.f;
}

// ---------------- prep: U -> UT[k][n(pad)] bf16 (+ optional Ubf[n][k]) -------
__global__ __launch_bounds__(256) void prep_u(const float* __restrict__ U,
                                              unsigned* __restrict__ UT,
                                              unsigned* __restrict__ Ubf)
{
    const int n0 = blockIdx.x * 64;
    const int k0 = blockIdx.y * 64;
    const int a  = threadIdx.x & 15;
    const int b  = threadIdx.x >> 4;
    const int n  = n0 + 4 * a;
    const int k  = k0 + 4 * b;

    float r[4][4];
    #pragma unroll
    for (int j = 0; j < 4; ++j) {
        int nr = n + j;
        if (nr < N_NODES) {
            f32x4 v = *reinterpret_cast<const f32x4*>(U + (long)nr * K_EIG + k);
            r[j][0] = v[0]; r[j][1] = v[1]; r[j][2] = v[2]; r[j][3] = v[3];
        } else {
            r[j][0] = r[j][1] = r[j][2] = r[j][3] = 0.f;
        }
    }
    #pragma unroll
    for (int i = 0; i < 4; ++i) {
        unsigned* p = UT + ((long)(k + i) * NPAD + n) / 2;
        p[0] = pk2(r[0][i], r[1][i]);
        p[1] = pk2(r[2][i], r[3][i]);
    }
    if (Ubf) {
        #pragma unroll
        for (int j = 0; j < 4; ++j) {
            int nr = n + j;
            if (nr < N_NODES) {
                unsigned* p = Ubf + ((long)nr * K_EIG + k) / 2;
                p[0] = pk2(r[j][0], r[j][1]);
                p[1] = pk2(r[j][2], r[j][3]);
            }
        }
    }
}

// ---------------- prep: x -> xT[f][n(pad)] bf16 ------------------------------
__global__ __launch_bounds__(256) void prep_x(const float* __restrict__ x,
                                              unsigned* __restrict__ xT)
{
    const int n0 = blockIdx.x * 64;
    const int f0 = blockIdx.y * 64;
    const int a  = threadIdx.x & 15;
    const int b  = threadIdx.x >> 4;
    const int n  = n0 + 4 * a;
    const int f  = f0 + 4 * b;

    float r[4][4];
    #pragma unroll
    for (int j = 0; j < 4; ++j) {
        int nr = n + j;
        if (nr < N_NODES) {
            f32x4 v = *reinterpret_cast<const f32x4*>(x + (long)nr * F_DIM + f);
            r[j][0] = v[0]; r[j][1] = v[1]; r[j][2] = v[2]; r[j][3] = v[3];
        } else {
            r[j][0] = r[j][1] = r[j][2] = r[j][3] = 0.f;
        }
    }
    #pragma unroll
    for (int i = 0; i < 4; ++i) {
        unsigned* p = xT + ((long)(f + i) * NPAD + n) / 2;
        p[0] = pk2(r[0][i], r[1][i]);
        p[1] = pk2(r[2][i], r[3][i]);
    }
}

// ---------------- GEMM1: partial[split][f][k] = sum_n UT[k][n]*xT[f][n] ------
// Register double-buffered: next-iter loads issue before current MFMAs.
__global__ __launch_bounds__(256) void k_spec(
    const unsigned short* __restrict__ UT, const unsigned short* __restrict__ xT,
    unsigned short* __restrict__ partial)
{
    const int kt    = blockIdx.x;
    const int split = blockIdx.y;
    const int tid   = threadIdx.x;
    const int wid   = tid >> 6;
    const int lane  = tid & 63;
    const int h     = lane >> 4;
    const int m     = lane & 15;
    const int k0    = kt * 64;
    const int f0    = wid * 32;
    const int nbeg  = split * CHUNK;

    f32x4 acc[4][2];
    #pragma unroll
    for (int s = 0; s < 4; ++s)
        #pragma unroll
        for (int t = 0; t < 2; ++t)
            #pragma unroll
            for (int e = 0; e < 4; ++e) acc[s][t][e] = 0.f;

    const unsigned short* Abase = UT + (long)(k0 + m) * NPAD + 8 * h;
    const unsigned short* Bbase = xT + (long)(f0 + m) * NPAD + 8 * h;

    bf16x8 aC[4], bC[2];
    #pragma unroll
    for (int s = 0; s < 4; ++s)
        aC[s] = *reinterpret_cast<const bf16x8*>(Abase + (long)16 * s * NPAD + nbeg);
    #pragma unroll
    for (int t = 0; t < 2; ++t)
        bC[t] = *reinterpret_cast<const bf16x8*>(Bbase + (long)16 * t * NPAD + nbeg);

    for (int nb = nbeg; nb < nbeg + CHUNK; nb += 32) {
        // prefetch next iteration (clamped to start on the last iter; harmless)
        int nn = (nb + 32 < nbeg + CHUNK) ? nb + 32 : nbeg;
        bf16x8 aN[4], bN[2];
        #pragma unroll
        for (int s = 0; s < 4; ++s)
            aN[s] = *reinterpret_cast<const bf16x8*>(Abase + (long)16 * s * NPAD + nn);
        #pragma unroll
        for (int t = 0; t < 2; ++t)
            bN[t] = *reinterpret_cast<const bf16x8*>(Bbase + (long)16 * t * NPAD + nn);

        #pragma unroll
        for (int s = 0; s < 4; ++s)
            #pragma unroll
            for (int t = 0; t < 2; ++t)
                acc[s][t] = __builtin_amdgcn_mfma_f32_16x16x32_bf16(
                    aC[s], bC[t], acc[s][t], 0, 0, 0);

        #pragma unroll
        for (int s = 0; s < 4; ++s) aC[s] = aN[s];
        #pragma unroll
        for (int t = 0; t < 2; ++t) bC[t] = bN[t];
    }

    unsigned short* pbase = partial + (long)split * (F_DIM * K_EIG);
    #pragma unroll
    for (int s = 0; s < 4; ++s)
        #pragma unroll
        for (int t = 0; t < 2; ++t) {
            int k = k0 + 16 * s + 4 * h;
            int f = f0 + 16 * t + m;
            s16x4 v;
            #pragma unroll
            for (int r = 0; r < 4; ++r) v[r] = f2bf(acc[s][t][r]);
            *reinterpret_cast<s16x4*>(pbase + (long)f * K_EIG + k) = v;
        }
}

// ---------------- reduce partials, fold g, emit bf16 spec --------------------
__global__ __launch_bounds__(256) void k_reduce(
    const unsigned short* __restrict__ partial, const float* __restrict__ g,
    unsigned short* __restrict__ specbf)
{
    int idx = blockIdx.x * 256 + threadIdx.x;   // 0..65535
    float s = 0.f;
    #pragma unroll 8
    for (int p = 0; p < NSPLITS; ++p)
        s += bf2f(partial[(long)p * (F_DIM * K_EIG) + idx]);
    int k = idx & (K_EIG - 1);
    specbf[idx] = (unsigned short)f2bf(s * g[k]);
}

// ---------------- GEMM2 (tier 1): out = relu(Ubf @ specbf^T) -----------------
// 64n x 128f per block, 782 blocks; wave = 32n x 64f; reg double-buffered.
__global__ __launch_bounds__(256) void k_out_bf(
    const unsigned short* __restrict__ Ubf,
    const unsigned short* __restrict__ specbf,
    float* __restrict__ out)
{
    const int tid  = threadIdx.x;
    const int wid  = tid >> 6;
    const int lane = tid & 63;
    const int h = lane >> 4, m = lane & 15;
    const int wr = wid >> 1, wc = wid & 1;
    const int nbase = blockIdx.x * 64 + wr * 32;
    const int fbase = wc * 64;

    const unsigned short* Arow[2];
    #pragma unroll
    for (int i = 0; i < 2; ++i) {
        int n  = nbase + 16 * i + m;
        int nc = (n < N_NODES) ? n : (N_NODES - 1);
        Arow[i] = Ubf + (long)nc * K_EIG + 8 * h;
    }
    const unsigned short* Brow = specbf + (long)(fbase + m) * K_EIG + 8 * h;

    f32x4 acc[2][4];
    #pragma unroll
    for (int i = 0; i < 2; ++i)
        #pragma unroll
        for (int t = 0; t < 4; ++t)
            #pragma unroll
            for (int e = 0; e < 4; ++e) acc[i][t][e] = 0.f;

    bf16x8 aC[2], bC[4];
    #pragma unroll
    for (int i = 0; i < 2; ++i)
        aC[i] = *reinterpret_cast<const bf16x8*>(Arow[i]);
    #pragma unroll
    for (int t = 0; t < 4; ++t)
        bC[t] = *reinterpret_cast<const bf16x8*>(Brow + (long)16 * t * K_EIG);

    for (int kb = 0; kb < K_EIG; kb += 32) {
        int kn = (kb + 32 < K_EIG) ? kb + 32 : 0;   // clamp; last-iter load unused
        bf16x8 aN[2], bN[4];
        #pragma unroll
        for (int i = 0; i < 2; ++i)
            aN[i] = *reinterpret_cast<const bf16x8*>(Arow[i] + kn);
        #pragma unroll
        for (int t = 0; t < 4; ++t)
            bN[t] = *reinterpret_cast<const bf16x8*>(Brow + (long)16 * t * K_EIG + kn);

        #pragma unroll
        for (int i = 0; i < 2; ++i)
            #pragma unroll
            for (int t = 0; t < 4; ++t)
                acc[i][t] = __builtin_amdgcn_mfma_f32_16x16x32_bf16(
                    aC[i], bC[t], acc[i][t], 0, 0, 0);

        #pragma unroll
        for (int i = 0; i < 2; ++i) aC[i] = aN[i];
        #pragma unroll
        for (int t = 0; t < 4; ++t) bC[t] = bN[t];
    }

    #pragma unroll
    for (int i = 0; i < 2; ++i)
        #pragma unroll
        for (int r = 0; r < 4; ++r) {
            int nn = nbase + 16 * i + 4 * h + r;
            if (nn < N_NODES) {
                float* orow = out + (long)nn * F_DIM + fbase + m;
                #pragma unroll
                for (int t = 0; t < 4; ++t)
                    orow[16 * t] = fmaxf(acc[i][t][r], 0.f);
            }
        }
}

// ---------------- GEMM2 (tier 2): f32 U, reg double-buffered -----------------
__global__ __launch_bounds__(256) void k_out_f32(
    const float* __restrict__ U, const unsigned short* __restrict__ specbf,
    float* __restrict__ out)
{
    const int tid  = threadIdx.x;
    const int wid  = tid >> 6;
    const int lane = tid & 63;
    const int h = lane >> 4, m = lane & 15;
    const int wr = wid >> 1, wc = wid & 1;
    const int nbase = blockIdx.x * 64 + wr * 32;
    const int fbase = wc * 64;

    const float* Arow[2];
    #pragma unroll
    for (int i = 0; i < 2; ++i) {
        int n  = nbase + 16 * i + m;
        int nc = (n < N_NODES) ? n : (N_NODES - 1);
        Arow[i] = U + (long)nc * K_EIG + 8 * h;
    }
    const unsigned short* Brow = specbf + (long)(fbase + m) * K_EIG + 8 * h;

    f32x4 acc[2][4];
    #pragma unroll
    for (int i = 0; i < 2; ++i)
        #pragma unroll
        for (int t = 0; t < 4; ++t)
            #pragma unroll
            for (int e = 0; e < 4; ++e) acc[i][t][e] = 0.f;

    f32x4 loC[2], hiC[2]; bf16x8 bC[4];
    #pragma unroll
    for (int i = 0; i < 2; ++i) {
        loC[i] = *reinterpret_cast<const f32x4*>(Arow[i]);
        hiC[i] = *reinterpret_cast<const f32x4*>(Arow[i] + 4);
    }
    #pragma unroll
    for (int t = 0; t < 4; ++t)
        bC[t] = *reinterpret_cast<const bf16x8*>(Brow + (long)16 * t * K_EIG);

    for (int kb = 0; kb < K_EIG; kb += 32) {
        int kn = (kb + 32 < K_EIG) ? kb + 32 : 0;
        f32x4 loN[2], hiN[2]; bf16x8 bN[4];
        #pragma unroll
        for (int i = 0; i < 2; ++i) {
            loN[i] = *reinterpret_cast<const f32x4*>(Arow[i] + kn);
            hiN[i] = *reinterpret_cast<const f32x4*>(Arow[i] + kn + 4);
        }
        #pragma unroll
        for (int t = 0; t < 4; ++t)
            bN[t] = *reinterpret_cast<const bf16x8*>(Brow + (long)16 * t * K_EIG + kn);

        bf16x8 a[2];
        #pragma unroll
        for (int i = 0; i < 2; ++i)
            #pragma unroll
            for (int j = 0; j < 4; ++j) {
                a[i][j]     = f2bf(loC[i][j]);
                a[i][j + 4] = f2bf(hiC[i][j]);
            }
        #pragma unroll
        for (int i = 0; i < 2; ++i)
            #pragma unroll
            for (int t = 0; t < 4; ++t)
                acc[i][t] = __builtin_amdgcn_mfma_f32_16x16x32_bf16(
                    a[i], bC[t], acc[i][t], 0, 0, 0);

        #pragma unroll
        for (int i = 0; i < 2; ++i) { loC[i] = loN[i]; hiC[i] = hiN[i]; }
        #pragma unroll
        for (int t = 0; t < 4; ++t) bC[t] = bN[t];
    }

    #pragma unroll
    for (int i = 0; i < 2; ++i)
        #pragma unroll
        for (int r = 0; r < 4; ++r) {
            int nn = nbase + 16 * i + 4 * h + r;
            if (nn < N_NODES) {
                float* orow = out + (long)nn * F_DIM + fbase + m;
                #pragma unroll
                for (int t = 0; t < 4; ++t)
                    orow[16 * t] = fmaxf(acc[i][t][r], 0.f);
            }
        }
}

// =================== deep fallback (round-1) if ws tiny ======================
__global__ __launch_bounds__(256) void k_spec_v1(
    const float* __restrict__ U, const float* __restrict__ g,
    const float* __restrict__ x, float* __restrict__ specT)
{
    const int kt    = blockIdx.x;
    const int split = blockIdx.y;
    const int tid   = threadIdx.x;
    const int wid   = tid >> 6;
    const int lane  = tid & 63;
    const int h     = lane >> 4;
    const int m     = lane & 15;
    const int k0 = kt * 64;
    const int f0 = wid * 32;
    const int chunk1 = 782;
    const int n_start = split * chunk1;
    int n_end = n_start + chunk1;
    if (n_end > N_NODES) n_end = N_NODES;

    f32x4 acc[4][2];
    #pragma unroll
    for (int s = 0; s < 4; ++s)
        #pragma unroll
        for (int t = 0; t < 2; ++t)
            #pragma unroll
            for (int e = 0; e < 4; ++e) acc[s][t][e] = 0.f;

    for (int nb = n_start; nb < n_end; nb += 32) {
        bf16x8 a[4]; bf16x8 b[2];
        const int nrow = nb + 8 * h;
        #pragma unroll
        for (int j = 0; j < 8; ++j) {
            int nn = nrow + j;
            bool valid = (nn < n_end);
            int nc = valid ? nn : (n_end - 1);
            const float* Urow = U + (long)nc * K_EIG + k0 + m;
            const float* Xrow = x + (long)nc * F_DIM + f0 + m;
            #pragma unroll
            for (int s = 0; s < 4; ++s) {
                short bv = f2bf(Urow[16 * s]);
                a[s][j] = valid ? bv : (short)0;
            }
            #pragma unroll
            for (int t = 0; t < 2; ++t) {
                short bv = f2bf(Xrow[16 * t]);
                b[t][j] = valid ? bv : (short)0;
            }
        }
        #pragma unroll
        for (int s = 0; s < 4; ++s)
            #pragma unroll
            for (int t = 0; t < 2; ++t)
                acc[s][t] = __builtin_amdgcn_mfma_f32_16x16x32_bf16(
                    a[s], b[t], acc[s][t], 0, 0, 0);
    }
    #pragma unroll
    for (int s = 0; s < 4; ++s)
        #pragma unroll
        for (int t = 0; t < 2; ++t)
            #pragma unroll
            for (int r = 0; r < 4; ++r) {
                int k = k0 + 16 * s + 4 * h + r;
                int f = f0 + 16 * t + m;
                atomicAdd(&specT[(long)f * K_EIG + k], acc[s][t][r] * g[k]);
            }
}

__global__ __launch_bounds__(256) void k_out_v1(
    const float* __restrict__ U, const float* __restrict__ specT,
    float* __restrict__ out)
{
    const int tid  = threadIdx.x;
    const int wid  = tid >> 6;
    const int lane = tid & 63;
    const int h = lane >> 4, m = lane & 15;
    const int wr = wid >> 1, wc = wid & 1;
    const int nbase = blockIdx.x * 128 + wr * 64;
    const int fbase = wc * 64;

    f32x4 acc[4][4];
    #pragma unroll
    for (int i = 0; i < 4; ++i)
        #pragma unroll
        for (int t = 0; t < 4; ++t)
            #pragma unroll
            for (int e = 0; e < 4; ++e) acc[i][t][e] = 0.f;

    for (int kb = 0; kb < K_EIG; kb += 32) {
        bf16x8 a[4], b[4];
        #pragma unroll
        for (int i = 0; i < 4; ++i) {
            int nn = nbase + 16 * i + m;
            bool valid = (nn < N_NODES);
            int nc = valid ? nn : (N_NODES - 1);
            const f32x4* p = reinterpret_cast<const f32x4*>(
                U + (long)nc * K_EIG + kb + 8 * h);
            f32x4 lo = p[0], hi = p[1];
            #pragma unroll
            for (int j = 0; j < 4; ++j) {
                short b0 = f2bf(lo[j]), b1 = f2bf(hi[j]);
                a[i][j]     = valid ? b0 : (short)0;
                a[i][j + 4] = valid ? b1 : (short)0;
            }
        }
        #pragma unroll
        for (int t = 0; t < 4; ++t) {
            const f32x4* p = reinterpret_cast<const f32x4*>(
                specT + (long)(fbase + 16 * t + m) * K_EIG + kb + 8 * h);
            f32x4 lo = p[0], hi = p[1];
            #pragma unroll
            for (int j = 0; j < 4; ++j) {
                b[t][j]     = f2bf(lo[j]);
                b[t][j + 4] = f2bf(hi[j]);
            }
        }
        #pragma unroll
        for (int i = 0; i < 4; ++i)
            #pragma unroll
            for (int t = 0; t < 4; ++t)
                acc[i][t] = __builtin_amdgcn_mfma_f32_16x16x32_bf16(
                    a[i], b[t], acc[i][t], 0, 0, 0);
    }
    #pragma unroll
    for (int i = 0; i < 4; ++i)
        #pragma unroll
        for (int r = 0; r < 4; ++r) {
            int nn = nbase + 16 * i + 4 * h + r;
            if (nn < N_NODES) {
                float* orow = out + (long)nn * F_DIM + fbase + m;
                #pragma unroll
                for (int t = 0; t < 4; ++t)
                    orow[16 * t] = fmaxf(acc[i][t][r], 0.f);
            }
        }
}

// ============================================================================
extern "C" void kernel_launch(void* const* d_in, const int* in_sizes, int n_in,
                              void* d_out, int out_size, void* d_ws, size_t ws_size,
                              hipStream_t stream) {
    const float* U = (const float*)d_in[0];
    const float* g = (const float*)d_in[1];
    const float* x = (const float*)d_in[2];
    float* out = (float*)d_out;

    // ws layout (bytes)
    const size_t OFF_UT    = 0;                 // 512*51200*2       = 52,428,800
    const size_t OFF_XT    = 52428800;          // 128*51200*2       = 13,107,200
    const size_t OFF_PART  = 65536000;          // 200*128*512*2     = 26,214,400
    const size_t OFF_SPECB = 91750400;          // 128*512*2         =    131,072
    const size_t WS_MID    = 91881472;
    const size_t OFF_UBF   = 91881472;          // 50000*512*2       = 51,200,000
    const size_t WS_FULL   = 143081472;

    if (ws_size >= WS_MID) {
        const bool full = (ws_size >= WS_FULL);
        unsigned*       UT     = (unsigned*)((char*)d_ws + OFF_UT);
        unsigned*       xT     = (unsigned*)((char*)d_ws + OFF_XT);
        unsigned short* part   = (unsigned short*)((char*)d_ws + OFF_PART);
        unsigned short* specbf = (unsigned short*)((char*)d_ws + OFF_SPECB);
        unsigned*       Ubf    = full ? (unsigned*)((char*)d_ws + OFF_UBF) : nullptr;

        dim3 gu(NPAD / 64, K_EIG / 64);   // 800 x 8
        prep_u<<<gu, 256, 0, stream>>>(U, UT, Ubf);

        dim3 gx(NPAD / 64, F_DIM / 64);   // 800 x 2
        prep_x<<<gx, 256, 0, stream>>>(x, xT);

        dim3 g1(K_EIG / 64, NSPLITS);     // 8 x 200 = 1600 blocks
        k_spec<<<g1, 256, 0, stream>>>((const unsigned short*)UT,
                                       (const unsigned short*)xT, part);

        k_reduce<<<(K_EIG * F_DIM) / 256, 256, 0, stream>>>(part, g, specbf);

        int nb2 = (N_NODES + 63) / 64;    // 782
        if (full)
            k_out_bf<<<nb2, 256, 0, stream>>>((const unsigned short*)Ubf,
                                              specbf, out);
        else
            k_out_f32<<<nb2, 256, 0, stream>>>(U, specbf, out);
    } else {
        float* specT = (float*)d_ws;      // 256 KB
        hipMemsetAsync(specT, 0, (size_t)K_EIG * F_DIM * sizeof(float), stream);
        dim3 g1(K_EIG / 64, 64);
        k_spec_v1<<<g1, 256, 0, stream>>>(U, g, x, specT);
        int nb2 = (N_NODES + 127) / 128;
        k_out_v1<<<nb2, 256, 0, stream>>>(U, specT, out);
    }
}

// Round 6
// 119.405 us; speedup vs baseline: 1.4381x; 1.3676x over previous
//
#include <hip/hip_runtime.h>
#include <hip/hip_bf16.h>

#define N_NODES 50000
#define K_EIG   512
#define F_DIM   128
#define NPAD    51200     // 200 splits * 256
#define NSPLITS 200
#define CHUNK   256

typedef __attribute__((ext_vector_type(8))) short bf16x8;
typedef __attribute__((ext_vector_type(4))) short s16x4;
typedef __attribute__((ext_vector_type(4))) float f32x4;

static __device__ __forceinline__ unsigned pk2(float lo, float hi) {
    unsigned short a = __builtin_bit_cast(unsigned short, __float2bfloat16(lo));
    unsigned short b = __builtin_bit_cast(unsigned short, __float2bfloat16(hi));
    return ((unsigned)b << 16) | (unsigned)a;
}

static __device__ __forceinline__ short f2bf(float f) {
    union { float f; unsigned u; } v; v.f = f;
    unsigned r = v.u + 0x7fffu + ((v.u >> 16) & 1u);   // RNE
    return (short)(r >> 16);
}

static __device__ __forceinline__ float bf2f(unsigned short u) {
    union { unsigned u; float f; } v; v.u = ((unsigned)u) << 16;
    return v.f;
}

// ---------------- prep: x -> xT[f][n(pad)] bf16 ------------------------------
__global__ __launch_bounds__(256) void prep_x(const float* __restrict__ x,
                                              unsigned* __restrict__ xT)
{
    const int n0 = blockIdx.x * 64;
    const int f0 = blockIdx.y * 64;
    const int a  = threadIdx.x & 15;
    const int b  = threadIdx.x >> 4;
    const int n  = n0 + 4 * a;
    const int f  = f0 + 4 * b;

    float r[4][4];
    #pragma unroll
    for (int j = 0; j < 4; ++j) {
        int nr = n + j;
        if (nr < N_NODES) {
            f32x4 v = *reinterpret_cast<const f32x4*>(x + (long)nr * F_DIM + f);
            r[j][0] = v[0]; r[j][1] = v[1]; r[j][2] = v[2]; r[j][3] = v[3];
        } else {
            r[j][0] = r[j][1] = r[j][2] = r[j][3] = 0.f;
        }
    }
    #pragma unroll
    for (int i = 0; i < 4; ++i) {
        unsigned* p = xT + ((long)(f + i) * NPAD + n) / 2;
        p[0] = pk2(r[0][i], r[1][i]);
        p[1] = pk2(r[2][i], r[3][i]);
    }
}

// ---------------- fused GEMM1: LDS-transpose of U + MFMA + Ubf side-product --
// partial[split][f][k0:64] = sum_n U[n][k]*x[n][f];  Ubf[n][k] = bf16(U[n][k]).
// grid (8 kt, 200 splits), 256 thr. LDS tile [64k][64n] bf16, XOR-swizzled.
__global__ __launch_bounds__(256) void k_spec_f(
    const float* __restrict__ U, const unsigned short* __restrict__ xT,
    unsigned* __restrict__ Ubf, unsigned short* __restrict__ partial)
{
    __shared__ unsigned char lds[64 * 128];   // 8 KB

    const int kt    = blockIdx.x;
    const int split = blockIdx.y;
    const int tid   = threadIdx.x;
    const int wid   = tid >> 6;
    const int lane  = tid & 63;
    const int h     = lane >> 4;
    const int m     = lane & 15;
    const int k0    = kt * 64;
    const int f0    = wid * 32;
    const int nbeg  = split * CHUNK;

    // staging mapping: adjacent lanes span k (coalesced U reads / Ubf writes)
    const int kq = tid & 15;    // k-quad: k_local = 4*kq
    const int nq = tid >> 4;    // n-quad: n_local = 4*nq

    f32x4 acc[4][2];
    #pragma unroll
    for (int s = 0; s < 4; ++s)
        #pragma unroll
        for (int t = 0; t < 2; ++t)
            #pragma unroll
            for (int e = 0; e < 4; ++e) acc[s][t][e] = 0.f;

    const unsigned short* Bbase = xT + (long)(f0 + m) * NPAD + 8 * h;

    for (int step = 0; step < 4; ++step) {
        const int ntile = nbeg + 64 * step;

        // prefetch B fragments for both substeps (global, L3-hot)
        bf16x8 bfr[2][2];
        #pragma unroll
        for (int sub = 0; sub < 2; ++sub)
            #pragma unroll
            for (int t = 0; t < 2; ++t)
                bfr[sub][t] = *reinterpret_cast<const bf16x8*>(
                    Bbase + (long)16 * t * NPAD + ntile + 32 * sub);

        // load U micro-tile 4n x 4k (rows 256B-coalesced across kq lanes)
        float r[4][4];
        #pragma unroll
        for (int j = 0; j < 4; ++j) {
            int n = ntile + 4 * nq + j;
            if (n < N_NODES) {
                f32x4 v = *reinterpret_cast<const f32x4*>(
                    U + (long)n * K_EIG + k0 + 4 * kq);
                r[j][0] = v[0]; r[j][1] = v[1]; r[j][2] = v[2]; r[j][3] = v[3];
            } else {
                r[j][0] = r[j][1] = r[j][2] = r[j][3] = 0.f;
            }
        }

        // side-product: Ubf bf16 rows (128B-coalesced across kq lanes)
        #pragma unroll
        for (int j = 0; j < 4; ++j) {
            int n = ntile + 4 * nq + j;
            if (n < N_NODES) {
                unsigned* p = Ubf + ((long)n * K_EIG + k0 + 4 * kq) / 2;
                p[0] = pk2(r[j][0], r[j][1]);
                p[1] = pk2(r[j][2], r[j][3]);
            }
        }

        __syncthreads();   // prev step's LDS reads done
        // micro-transpose to LDS [k][n] bf16, byte ^= (k&7)<<4 swizzle
        #pragma unroll
        for (int i = 0; i < 4; ++i) {
            int kl = 4 * kq + i;
            unsigned lo = pk2(r[0][i], r[1][i]);   // n_l = 4nq, 4nq+1
            unsigned hi = pk2(r[2][i], r[3][i]);   // n_l = 4nq+2, 4nq+3
            int byte = (kl * 128 + 8 * nq) ^ ((kl & 7) << 4);
            *reinterpret_cast<unsigned long long*>(lds + byte) =
                ((unsigned long long)hi << 32) | (unsigned long long)lo;
        }
        __syncthreads();   // tile ready

        #pragma unroll
        for (int sub = 0; sub < 2; ++sub) {
            bf16x8 af[4];
            #pragma unroll
            for (int s = 0; s < 4; ++s) {
                int row  = 16 * s + m;
                int byte = (row * 128 + 64 * sub + 16 * h) ^ ((m & 7) << 4);
                af[s] = *reinterpret_cast<const bf16x8*>(lds + byte);
            }
            #pragma unroll
            for (int s = 0; s < 4; ++s)
                #pragma unroll
                for (int t = 0; t < 2; ++t)
                    acc[s][t] = __builtin_amdgcn_mfma_f32_16x16x32_bf16(
                        af[s], bfr[sub][t], acc[s][t], 0, 0, 0);
        }
    }

    unsigned short* pbase = partial + (long)split * (F_DIM * K_EIG);
    #pragma unroll
    for (int s = 0; s < 4; ++s)
        #pragma unroll
        for (int t = 0; t < 2; ++t) {
            int k = k0 + 16 * s + 4 * h;
            int f = f0 + 16 * t + m;
            s16x4 v;
            #pragma unroll
            for (int rr = 0; rr < 4; ++rr) v[rr] = f2bf(acc[s][t][rr]);
            *reinterpret_cast<s16x4*>(pbase + (long)f * K_EIG + k) = v;
        }
}

// ---------------- reduce partials, fold g, emit bf16 spec --------------------
__global__ __launch_bounds__(256) void k_reduce(
    const unsigned short* __restrict__ partial, const float* __restrict__ g,
    unsigned short* __restrict__ specbf)
{
    int idx = blockIdx.x * 256 + threadIdx.x;   // 0..65535
    float s = 0.f;
    #pragma unroll 8
    for (int p = 0; p < NSPLITS; ++p)
        s += bf2f(partial[(long)p * (F_DIM * K_EIG) + idx]);
    int k = idx & (K_EIG - 1);
    specbf[idx] = (unsigned short)f2bf(s * g[k]);
}

// ---------------- GEMM2: out = relu(Ubf @ specbf^T), reg double-buffered -----
__global__ __launch_bounds__(256) void k_out_bf(
    const unsigned short* __restrict__ Ubf,
    const unsigned short* __restrict__ specbf,
    float* __restrict__ out)
{
    const int tid  = threadIdx.x;
    const int wid  = tid >> 6;
    const int lane = tid & 63;
    const int h = lane >> 4, m = lane & 15;
    const int wr = wid >> 1, wc = wid & 1;
    const int nbase = blockIdx.x * 64 + wr * 32;
    const int fbase = wc * 64;

    const unsigned short* Arow[2];
    #pragma unroll
    for (int i = 0; i < 2; ++i) {
        int n  = nbase + 16 * i + m;
        int nc = (n < N_NODES) ? n : (N_NODES - 1);
        Arow[i] = Ubf + (long)nc * K_EIG + 8 * h;
    }
    const unsigned short* Brow = specbf + (long)(fbase + m) * K_EIG + 8 * h;

    f32x4 acc[2][4];
    #pragma unroll
    for (int i = 0; i < 2; ++i)
        #pragma unroll
        for (int t = 0; t < 4; ++t)
            #pragma unroll
            for (int e = 0; e < 4; ++e) acc[i][t][e] = 0.f;

    bf16x8 aC[2], bC[4];
    #pragma unroll
    for (int i = 0; i < 2; ++i)
        aC[i] = *reinterpret_cast<const bf16x8*>(Arow[i]);
    #pragma unroll
    for (int t = 0; t < 4; ++t)
        bC[t] = *reinterpret_cast<const bf16x8*>(Brow + (long)16 * t * K_EIG);

    for (int kb = 0; kb < K_EIG; kb += 32) {
        int kn = (kb + 32 < K_EIG) ? kb + 32 : 0;   // clamp; last-iter load unused
        bf16x8 aN[2], bN[4];
        #pragma unroll
        for (int i = 0; i < 2; ++i)
            aN[i] = *reinterpret_cast<const bf16x8*>(Arow[i] + kn);
        #pragma unroll
        for (int t = 0; t < 4; ++t)
            bN[t] = *reinterpret_cast<const bf16x8*>(Brow + (long)16 * t * K_EIG + kn);

        #pragma unroll
        for (int i = 0; i < 2; ++i)
            #pragma unroll
            for (int t = 0; t < 4; ++t)
                acc[i][t] = __builtin_amdgcn_mfma_f32_16x16x32_bf16(
                    aC[i], bC[t], acc[i][t], 0, 0, 0);

        #pragma unroll
        for (int i = 0; i < 2; ++i) aC[i] = aN[i];
        #pragma unroll
        for (int t = 0; t < 4; ++t) bC[t] = bN[t];
    }

    #pragma unroll
    for (int i = 0; i < 2; ++i)
        #pragma unroll
        for (int r = 0; r < 4; ++r) {
            int nn = nbase + 16 * i + 4 * h + r;
            if (nn < N_NODES) {
                float* orow = out + (long)nn * F_DIM + fbase + m;
                #pragma unroll
                for (int t = 0; t < 4; ++t)
                    orow[16 * t] = fmaxf(acc[i][t][r], 0.f);
            }
        }
}

// =================== deep fallback (round-1) if ws tiny ======================
__global__ __launch_bounds__(256) void k_spec_v1(
    const float* __restrict__ U, const float* __restrict__ g,
    const float* __restrict__ x, float* __restrict__ specT)
{
    const int kt    = blockIdx.x;
    const int split = blockIdx.y;
    const int tid   = threadIdx.x;
    const int wid   = tid >> 6;
    const int lane  = tid & 63;
    const int h     = lane >> 4;
    const int m     = lane & 15;
    const int k0 = kt * 64;
    const int f0 = wid * 32;
    const int chunk1 = 782;
    const int n_start = split * chunk1;
    int n_end = n_start + chunk1;
    if (n_end > N_NODES) n_end = N_NODES;

    f32x4 acc[4][2];
    #pragma unroll
    for (int s = 0; s < 4; ++s)
        #pragma unroll
        for (int t = 0; t < 2; ++t)
            #pragma unroll
            for (int e = 0; e < 4; ++e) acc[s][t][e] = 0.f;

    for (int nb = n_start; nb < n_end; nb += 32) {
        bf16x8 a[4]; bf16x8 b[2];
        const int nrow = nb + 8 * h;
        #pragma unroll
        for (int j = 0; j < 8; ++j) {
            int nn = nrow + j;
            bool valid = (nn < n_end);
            int nc = valid ? nn : (n_end - 1);
            const float* Urow = U + (long)nc * K_EIG + k0 + m;
            const float* Xrow = x + (long)nc * F_DIM + f0 + m;
            #pragma unroll
            for (int s = 0; s < 4; ++s) {
                short bv = f2bf(Urow[16 * s]);
                a[s][j] = valid ? bv : (short)0;
            }
            #pragma unroll
            for (int t = 0; t < 2; ++t) {
                short bv = f2bf(Xrow[16 * t]);
                b[t][j] = valid ? bv : (short)0;
            }
        }
        #pragma unroll
        for (int s = 0; s < 4; ++s)
            #pragma unroll
            for (int t = 0; t < 2; ++t)
                acc[s][t] = __builtin_amdgcn_mfma_f32_16x16x32_bf16(
                    a[s], b[t], acc[s][t], 0, 0, 0);
    }
    #pragma unroll
    for (int s = 0; s < 4; ++s)
        #pragma unroll
        for (int t = 0; t < 2; ++t)
            #pragma unroll
            for (int r = 0; r < 4; ++r) {
                int k = k0 + 16 * s + 4 * h + r;
                int f = f0 + 16 * t + m;
                atomicAdd(&specT[(long)f * K_EIG + k], acc[s][t][r] * g[k]);
            }
}

__global__ __launch_bounds__(256) void k_out_v1(
    const float* __restrict__ U, const float* __restrict__ specT,
    float* __restrict__ out)
{
    const int tid  = threadIdx.x;
    const int wid  = tid >> 6;
    const int lane = tid & 63;
    const int h = lane >> 4, m = lane & 15;
    const int wr = wid >> 1, wc = wid & 1;
    const int nbase = blockIdx.x * 128 + wr * 64;
    const int fbase = wc * 64;

    f32x4 acc[4][4];
    #pragma unroll
    for (int i = 0; i < 4; ++i)
        #pragma unroll
        for (int t = 0; t < 4; ++t)
            #pragma unroll
            for (int e = 0; e < 4; ++e) acc[i][t][e] = 0.f;

    for (int kb = 0; kb < K_EIG; kb += 32) {
        bf16x8 a[4], b[4];
        #pragma unroll
        for (int i = 0; i < 4; ++i) {
            int nn = nbase + 16 * i + m;
            bool valid = (nn < N_NODES);
            int nc = valid ? nn : (N_NODES - 1);
            const f32x4* p = reinterpret_cast<const f32x4*>(
                U + (long)nc * K_EIG + kb + 8 * h);
            f32x4 lo = p[0], hi = p[1];
            #pragma unroll
            for (int j = 0; j < 4; ++j) {
                short b0 = f2bf(lo[j]), b1 = f2bf(hi[j]);
                a[i][j]     = valid ? b0 : (short)0;
                a[i][j + 4] = valid ? b1 : (short)0;
            }
        }
        #pragma unroll
        for (int t = 0; t < 4; ++t) {
            const f32x4* p = reinterpret_cast<const f32x4*>(
                specT + (long)(fbase + 16 * t + m) * K_EIG + kb + 8 * h);
            f32x4 lo = p[0], hi = p[1];
            #pragma unroll
            for (int j = 0; j < 4; ++j) {
                b[t][j]     = f2bf(lo[j]);
                b[t][j + 4] = f2bf(hi[j]);
            }
        }
        #pragma unroll
        for (int i = 0; i < 4; ++i)
            #pragma unroll
            for (int t = 0; t < 4; ++t)
                acc[i][t] = __builtin_amdgcn_mfma_f32_16x16x32_bf16(
                    a[i], b[t], acc[i][t], 0, 0, 0);
    }
    #pragma unroll
    for (int i = 0; i < 4; ++i)
        #pragma unroll
        for (int r = 0; r < 4; ++r) {
            int nn = nbase + 16 * i + 4 * h + r;
            if (nn < N_NODES) {
                float* orow = out + (long)nn * F_DIM + fbase + m;
                #pragma unroll
                for (int t = 0; t < 4; ++t)
                    orow[16 * t] = fmaxf(acc[i][t][r], 0.f);
            }
        }
}

// ============================================================================
extern "C" void kernel_launch(void* const* d_in, const int* in_sizes, int n_in,
                              void* d_out, int out_size, void* d_ws, size_t ws_size,
                              hipStream_t stream) {
    const float* U = (const float*)d_in[0];
    const float* g = (const float*)d_in[1];
    const float* x = (const float*)d_in[2];
    float* out = (float*)d_out;

    // ws layout (bytes)
    const size_t OFF_XT    = 0;                 // 128*51200*2   = 13,107,200
    const size_t OFF_PART  = 13107200;          // 200*128*512*2 = 26,214,400
    const size_t OFF_SPECB = 39321600;          // 128*512*2     =    131,072
    const size_t OFF_UBF   = 39452672;          // 50000*512*2   = 51,200,000
    const size_t WS_NEEDED = 90652672;

    if (ws_size >= WS_NEEDED) {
        unsigned*       xT     = (unsigned*)((char*)d_ws + OFF_XT);
        unsigned short* part   = (unsigned short*)((char*)d_ws + OFF_PART);
        unsigned short* specbf = (unsigned short*)((char*)d_ws + OFF_SPECB);
        unsigned*       Ubf    = (unsigned*)((char*)d_ws + OFF_UBF);

        dim3 gx(NPAD / 64, F_DIM / 64);   // 800 x 2
        prep_x<<<gx, 256, 0, stream>>>(x, xT);

        dim3 g1(K_EIG / 64, NSPLITS);     // 8 x 200 = 1600 blocks
        k_spec_f<<<g1, 256, 0, stream>>>(U, (const unsigned short*)xT,
                                         Ubf, part);

        k_reduce<<<(K_EIG * F_DIM) / 256, 256, 0, stream>>>(part, g, specbf);

        int nb2 = (N_NODES + 63) / 64;    // 782
        k_out_bf<<<nb2, 256, 0, stream>>>((const unsigned short*)Ubf,
                                          specbf, out);
    } else {
        float* specT = (float*)d_ws;      // 256 KB
        hipMemsetAsync(specT, 0, (size_t)K_EIG * F_DIM * sizeof(float), stream);
        dim3 g1(K_EIG / 64, 64);
        k_spec_v1<<<g1, 256, 0, stream>>>(U, g, x, specT);
        int nb2 = (N_NODES + 127) / 128;
        k_out_v1<<<nb2, 256, 0, stream>>>(U, specT, out);
    }
}